// Round 1
// baseline (4146.111 us; speedup 1.0000x reference)
//
#include <hip/hip_runtime.h>
#include <math.h>

#define BDIM   8
#define TDIM   2048
#define DDIM   512
#define PDIM   8
#define NTOK   (BDIM * TDIM)        // 16384
#define KDIM   (DDIM * PDIM)        // 4096
#define EPSF   1e-6f

// ---------------- prep: breakpoint params ----------------
// pl[i*8+p] = pts[i][p-1], inv[i*8+p] = 1/(pts[i][p]-pts[i][p-1]) for p=1..7
__global__ void prep_params_kernel(const float* __restrict__ pts,
                                   float* __restrict__ pl,
                                   float* __restrict__ inv) {
    int i = blockIdx.x * blockDim.x + threadIdx.x;
    if (i >= DDIM) return;
    pl[i * 8] = 0.f;
    inv[i * 8] = 0.f;
    #pragma unroll
    for (int p = 1; p < 8; ++p) {
        float a = pts[i * 8 + p - 1];
        float b = pts[i * 8 + p];
        pl[i * 8 + p] = a;
        inv[i * 8 + p] = 1.0f / (b - a);
    }
}

// ---------------- prep: W = first-difference of v along P ----------------
// v: (D, P, D) -> W[k][o], k = i*8+p:  W = v[k][o] - (p>0 ? v[k-1][o] : 0)
__global__ void prep_w_kernel(const float* __restrict__ v, float* __restrict__ W) {
    int i4 = blockIdx.x * blockDim.x + threadIdx.x;  // float4 index
    if (i4 >= (KDIM * DDIM) / 4) return;
    int base = i4 * 4;
    int k = base >> 9;  // /512, all 4 elems in same k-row
    float4 cur = ((const float4*)v)[i4];
    if (k & 7) {
        float4 prev = ((const float4*)v)[i4 - (DDIM / 4)];
        cur.x -= prev.x; cur.y -= prev.y; cur.z -= prev.z; cur.w -= prev.w;
    }
    ((float4*)W)[i4] = cur;
}

// ---------------- fused ramp-GEMM ----------------
// out[n][o] = sum_k R[n][k] * W[k][o],  R computed on the fly from act.
// Tile: BN=128 rows x BO=128 cols x BK=16, 256 threads, 8x8 per thread.
#define BN 128
#define BO 128
#define BK 16

__launch_bounds__(256, 2)
__global__ void apl_gemm_kernel(const float* __restrict__ act,  // (NTOK, D)
                                const float* __restrict__ W,    // (KDIM, D)
                                const float* __restrict__ pl,
                                const float* __restrict__ inv,
                                float* __restrict__ out,        // (NTOK, D)
                                int apply_sigmoid) {
    __shared__ float As[BK][BN];      // [k][n]
    __shared__ float Bs[BK][BO + 4];  // [k][o], pad keeps 16B row alignment

    const int t  = threadIdx.x;
    const int o0 = blockIdx.x * BO;
    const int n0 = blockIdx.y * BN;
    const int tx = t & 15;   // o direction
    const int ty = t >> 4;   // n direction

    const int kq = t & 1;    // which 8-k half of BK
    const int nl = t >> 1;   // row within tile

    float acc[8][8];
    #pragma unroll
    for (int i = 0; i < 8; ++i)
        #pragma unroll
        for (int j = 0; j < 8; ++j) acc[i][j] = 0.f;

    for (int kk = 0; kk < KDIM; kk += BK) {
        // ---- stage A: compute ramp features (one x load -> 8 features) ----
        {
            int i = (kk >> 3) + kq;          // input dim for this 8-k group
            float xv = act[(n0 + nl) * DDIM + i];
            int kb = i * 8;
            As[kq * 8 + 0][nl] = 1.0f;       // constant feature (p=0)
            #pragma unroll
            for (int j = 1; j < 8; ++j) {
                float r = (xv - pl[kb + j]) * inv[kb + j];
                r = fminf(fmaxf(r, 0.f), 1.f);
                As[kq * 8 + j][nl] = r;
            }
        }
        // ---- stage B: W tile, float4-coalesced ----
        {
            #pragma unroll
            for (int r = 0; r < 2; ++r) {
                int e  = r * 256 + t;        // float4 elem id 0..511
                int kl = e >> 5;             // 32 float4 per row
                int o4 = e & 31;
                float4 wv = *(const float4*)&W[(kk + kl) * DDIM + o0 + o4 * 4];
                *(float4*)&Bs[kl][o4 * 4] = wv;
            }
        }
        __syncthreads();
        #pragma unroll
        for (int kl = 0; kl < BK; ++kl) {
            float4 a0 = *(const float4*)&As[kl][ty * 8];
            float4 a1 = *(const float4*)&As[kl][ty * 8 + 4];
            float4 b0 = *(const float4*)&Bs[kl][tx * 8];
            float4 b1 = *(const float4*)&Bs[kl][tx * 8 + 4];
            float a[8] = {a0.x, a0.y, a0.z, a0.w, a1.x, a1.y, a1.z, a1.w};
            float b[8] = {b0.x, b0.y, b0.z, b0.w, b1.x, b1.y, b1.z, b1.w};
            #pragma unroll
            for (int i = 0; i < 8; ++i)
                #pragma unroll
                for (int j = 0; j < 8; ++j)
                    acc[i][j] = fmaf(a[i], b[j], acc[i][j]);
        }
        __syncthreads();
    }
    // ---- epilogue ----
    #pragma unroll
    for (int i = 0; i < 8; ++i) {
        int n = n0 + ty * 8 + i;
        float r[8];
        #pragma unroll
        for (int j = 0; j < 8; ++j) {
            float val = acc[i][j];
            if (apply_sigmoid) val = 1.0f / (1.0f + expf(-val));
            r[j] = val;
        }
        *(float4*)&out[n * DDIM + o0 + tx * 8]     = make_float4(r[0], r[1], r[2], r[3]);
        *(float4*)&out[n * DDIM + o0 + tx * 8 + 4] = make_float4(r[4], r[5], r[6], r[7]);
    }
}

// ---------------- recurrence: chunked linear scan ----------------
// h[t] = (1-z[t]) h[t-1] + z[t] hbar[t],  h0 = 0.  16 chunks x 128 steps.
#define RC_CH 16
#define RC_L  (TDIM / RC_CH)      // 128
#define NCHAIN (BDIM * DDIM)      // 4096

__global__ void rec_pass1(const float* __restrict__ z, const float* __restrict__ hb,
                          float* __restrict__ Aout, float* __restrict__ Bout) {
    int tid = blockIdx.x * blockDim.x + threadIdx.x;  // 0..65535
    int c = tid >> 12;
    int chain = tid & 4095;
    int b = chain >> 9, d = chain & 511;
    int base = ((b * TDIM) + c * RC_L) * DDIM + d;
    float ap = 1.f, h = 0.f;
    for (int s = 0; s < RC_L; ++s) {
        float zz = z[base];
        float hh = hb[base];
        float a = 1.f - zz;
        h = fmaf(a, h, zz * hh);
        ap *= a;
        base += DDIM;
    }
    Aout[c * NCHAIN + chain] = ap;
    Bout[c * NCHAIN + chain] = h;
}

__global__ void rec_pass2(const float* __restrict__ A, const float* __restrict__ Bv,
                          float* __restrict__ hstart) {
    int chain = blockIdx.x * blockDim.x + threadIdx.x;
    if (chain >= NCHAIN) return;
    float h = 0.f;  // h0 = 0
    #pragma unroll
    for (int c = 0; c < RC_CH; ++c) {
        hstart[c * NCHAIN + chain] = h;
        h = fmaf(A[c * NCHAIN + chain], h, Bv[c * NCHAIN + chain]);
    }
}

// writes h in-place over z
__global__ void rec_pass3(float* __restrict__ z, const float* __restrict__ hb,
                          const float* __restrict__ hstart) {
    int tid = blockIdx.x * blockDim.x + threadIdx.x;
    int c = tid >> 12;
    int chain = tid & 4095;
    int b = chain >> 9, d = chain & 511;
    int base = ((b * TDIM) + c * RC_L) * DDIM + d;
    float h = hstart[c * NCHAIN + chain];
    for (int s = 0; s < RC_L; ++s) {
        float zz = z[base];
        float hh = hb[base];
        h = fmaf(1.f - zz, h, zz * hh);
        z[base] = h;
        base += DDIM;
    }
}

// ---------------- maxabs norm: one wave per row ----------------
__global__ void norm_kernel(const float* __restrict__ h, float* __restrict__ out) {
    int wave = threadIdx.x >> 6;
    int lane = threadIdx.x & 63;
    int n = blockIdx.x * 4 + wave;
    const float4* row = (const float4*)&h[n * DDIM];
    float4 v0 = row[lane];
    float4 v1 = row[lane + 64];
    float m = fmaxf(fmaxf(fabsf(v0.x), fabsf(v0.y)), fmaxf(fabsf(v0.z), fabsf(v0.w)));
    m = fmaxf(m, fmaxf(fmaxf(fabsf(v1.x), fabsf(v1.y)), fmaxf(fabsf(v1.z), fabsf(v1.w))));
    #pragma unroll
    for (int off = 32; off; off >>= 1) m = fmaxf(m, __shfl_xor(m, off, 64));
    float s = 1.0f / (m + EPSF);
    float4* orow = (float4*)&out[n * DDIM];
    orow[lane]      = make_float4(v0.x * s, v0.y * s, v0.z * s, v0.w * s);
    orow[lane + 64] = make_float4(v1.x * s, v1.y * s, v1.z * s, v1.w * s);
}

// ---------------- orchestration ----------------
extern "C" void kernel_launch(void* const* d_in, const int* in_sizes, int n_in,
                              void* d_out, int out_size, void* d_ws, size_t ws_size,
                              hipStream_t stream) {
    const float* x   = (const float*)d_in[0];
    const float* pz0 = (const float*)d_in[1];
    const float* vz0 = (const float*)d_in[2];
    const float* ph0 = (const float*)d_in[3];
    const float* vh0 = (const float*)d_in[4];
    const float* pz1 = (const float*)d_in[5];
    const float* vz1 = (const float*)d_in[6];
    const float* ph1 = (const float*)d_in[7];
    const float* vh1 = (const float*)d_in[8];
    const float* po  = (const float*)d_in[9];
    const float* vo  = (const float*)d_in[10];

    float* out_r = (float*)d_out;                    // final output, also z-scratch
    float* h1_r  = out_r + (size_t)NTOK * DDIM;
    float* h2_r  = h1_r + (size_t)NTOK * DDIM;

    char* wp = (char*)d_ws;
    float* W    = (float*)wp; wp += (size_t)KDIM * DDIM * 4;   // 8 MB
    float* pl   = (float*)wp; wp += KDIM * 4;
    float* invp = (float*)wp; wp += KDIM * 4;
    float* hbuf = (float*)wp; wp += (size_t)NTOK * DDIM * 4;   // 33.5 MB (h_bar)
    float* Ab   = (float*)wp; wp += RC_CH * NCHAIN * 4;
    float* Bb   = (float*)wp; wp += RC_CH * NCHAIN * 4;
    float* hs   = (float*)wp; wp += RC_CH * NCHAIN * 4;

    dim3 gemm_grid(DDIM / BO, NTOK / BN);  // (4, 128)

    auto apl = [&](const float* pts, const float* v, const float* actp,
                   float* o, int sig) {
        prep_params_kernel<<<2, 256, 0, stream>>>(pts, pl, invp);
        prep_w_kernel<<<(KDIM * DDIM / 4 + 255) / 256, 256, 0, stream>>>(v, W);
        apl_gemm_kernel<<<gemm_grid, 256, 0, stream>>>(actp, W, pl, invp, o, sig);
    };
    auto recur = [&](float* zb, float* hb) {  // h written in-place over zb
        rec_pass1<<<(RC_CH * NCHAIN) / 256, 256, 0, stream>>>(zb, hb, Ab, Bb);
        rec_pass2<<<NCHAIN / 256, 256, 0, stream>>>(Ab, Bb, hs);
        rec_pass3<<<(RC_CH * NCHAIN) / 256, 256, 0, stream>>>(zb, hb, hs);
    };

    // layer 1  (z staged in out_r region — free until final APL)
    apl(pz0, vz0, x, out_r, 1);
    apl(ph0, vh0, x, hbuf, 0);
    recur(out_r, hbuf);
    norm_kernel<<<NTOK / 4, 256, 0, stream>>>(out_r, h1_r);
    // layer 2
    apl(pz1, vz1, h1_r, out_r, 1);
    apl(ph1, vh1, h1_r, hbuf, 0);
    recur(out_r, hbuf);
    norm_kernel<<<NTOK / 4, 256, 0, stream>>>(out_r, h2_r);
    // output APL
    apl(po, vo, h2_r, out_r, 0);
}

// Round 3
// 868.987 us; speedup vs baseline: 4.7712x; 4.7712x over previous
//
#include <hip/hip_runtime.h>
#include <hip/hip_bf16.h>
#include <math.h>

#define BDIM   8
#define TDIM   2048
#define DDIM   512
#define PDIM   8
#define NTOK   (BDIM * TDIM)        // 16384
#define KDIM   (DDIM * PDIM)        // 4096
#define EPSF   1e-6f

typedef __attribute__((ext_vector_type(4))) float floatx4;
typedef __attribute__((ext_vector_type(8))) _Float16 half8;

// ---------------- prep: per-k feature params: feat = clamp(x*inv + ofs, 0, 1)
__global__ void prep_params_kernel(const float* __restrict__ pts,
                                   float2* __restrict__ prm) {
    int i = blockIdx.x * blockDim.x + threadIdx.x;
    if (i >= DDIM) return;
    prm[i * 8] = make_float2(0.f, 1.f);
    #pragma unroll
    for (int p = 1; p < 8; ++p) {
        float a = pts[i * 8 + p - 1];
        float b = pts[i * 8 + p];
        float inv = 1.0f / (b - a);
        prm[i * 8 + p] = make_float2(inv, -a * inv);
    }
}

// ---------------- prep: W -> fp16, first-differenced, k-octet-interleaved
// p=0 column zeroed (handled by fp32 bias); p>=1: v[p]-v[p-1]
__global__ void prep_wtt_kernel(const float* __restrict__ v,
                                unsigned short* __restrict__ Wtt) {
    int idx = blockIdx.x * blockDim.x + threadIdx.x;   // oct*512 + o
    if (idx >= (KDIM / 8) * DDIM) return;
    int oct = idx >> 9, o = idx & 511;
    unsigned short f8[8];
    float prev = v[(size_t)(oct * 8) * DDIM + o];
    f8[0] = 0;   // constant column -> fp32 bias instead
    #pragma unroll
    for (int p = 1; p < 8; ++p) {
        float cur = v[(size_t)(oct * 8 + p) * DDIM + o];
        float d = cur - prev;
        prev = cur;
        _Float16 hv = (_Float16)d;
        f8[p] = *reinterpret_cast<unsigned short*>(&hv);
    }
    *(uint4*)&Wtt[(size_t)idx * 8] = *(const uint4*)f8;
}

// ---------------- prep: fp32 bias[o] = sum_i v[i][0][o] ----------------
__global__ void prep_bias_kernel(const float* __restrict__ v,
                                 float* __restrict__ bias) {
    int o = blockIdx.x * blockDim.x + threadIdx.x;
    if (o >= DDIM) return;
    float s = 0.f;
    for (int i = 0; i < DDIM; ++i) s += v[(size_t)i * PDIM * DDIM + o];
    bias[o] = s;
}

// ---------------- fp32 transpose (N,D) -> (D,N) ----------------
__global__ void transpose_kernel(const float* __restrict__ in,
                                 float* __restrict__ outT) {
    __shared__ float tile[64][65];
    int d0 = blockIdx.x * 64, n0 = blockIdx.y * 64;
    int t = threadIdx.x;
    int col = t & 63, rb = t >> 6;
    #pragma unroll
    for (int r = 0; r < 16; ++r) {
        int row = r * 4 + rb;
        tile[row][col] = in[(size_t)(n0 + row) * DDIM + d0 + col];
    }
    __syncthreads();
    #pragma unroll
    for (int r = 0; r < 16; ++r) {
        int drow = r * 4 + rb;
        outT[(size_t)(d0 + drow) * NTOK + n0 + col] = tile[col][drow];
    }
}

// ---------------- fused ramp-feature MFMA GEMM (fp16 in, fp32 acc) ----------
__launch_bounds__(256, 2)
__global__ void apl_gemm_mfma(const float* __restrict__ actT,      // (D, N)
                              const unsigned short* __restrict__ Wtt,
                              const float2* __restrict__ prm,
                              const float* __restrict__ bias,
                              float* __restrict__ out,             // (N, D)
                              int sig) {
    __shared__ unsigned short As[128 * 40];      // [n][k], row stride 40 (pad)
    __shared__ unsigned short Bs[4 * 128 * 8];   // [k-octet][o][j]

    const int t = threadIdx.x;
    const int w = t >> 6, l = t & 63;
    const int o0 = blockIdx.x * 128, n0 = blockIdx.y * 128;
    const int wn = w & 1, wo = w >> 1;
    const int lm = l & 15, lq = l >> 4;

    floatx4 acc[4][4];
    #pragma unroll
    for (int a = 0; a < 4; ++a)
        #pragma unroll
        for (int b = 0; b < 4; ++b) acc[a][b] = (floatx4){0.f, 0.f, 0.f, 0.f};

    for (int iter = 0; iter < KDIM / 32; ++iter) {
        const int iu = __builtin_amdgcn_readfirstlane(iter * 4 + w);
        float2 pp[8];
        #pragma unroll
        for (int p = 0; p < 8; ++p) pp[p] = prm[iu * 8 + p];
        const float* xrow = actT + (size_t)iu * NTOK + n0;
        const unsigned short* wg = Wtt + ((size_t)iu * DDIM + o0) * 8;

        #pragma unroll
        for (int r = 0; r < 2; ++r) {
            int n = r * 64 + l;
            float xv = xrow[n];
            unsigned short f8[8];
            #pragma unroll
            for (int p = 0; p < 8; ++p) {
                float tt = fmaf(xv, pp[p].x, pp[p].y);
                tt = fminf(fmaxf(tt, 0.f), 1.f);
                _Float16 hv = (_Float16)tt;
                f8[p] = *reinterpret_cast<unsigned short*>(&hv);
            }
            *(uint4*)&As[n * 40 + w * 8] = *(const uint4*)f8;
            uint4 bv = *(const uint4*)(wg + (size_t)n * 8);
            *(uint4*)&Bs[w * 1024 + n * 8] = bv;
        }
        __syncthreads();

        half8 af[4], bfr[4];
        #pragma unroll
        for (int tn = 0; tn < 4; ++tn)
            af[tn] = *(const half8*)&As[(wn * 64 + tn * 16 + lm) * 40 + lq * 8];
        #pragma unroll
        for (int to = 0; to < 4; ++to)
            bfr[to] = *(const half8*)&Bs[lq * 1024 + (wo * 64 + to * 16 + lm) * 8];
        #pragma unroll
        for (int tn = 0; tn < 4; ++tn)
            #pragma unroll
            for (int to = 0; to < 4; ++to)
                acc[tn][to] = __builtin_amdgcn_mfma_f32_16x16x32_f16(
                    af[tn], bfr[to], acc[tn][to], 0, 0, 0);
        __syncthreads();
    }

    // epilogue: C/D layout col=lane&15, row=(lane>>4)*4+reg; add fp32 bias
    #pragma unroll
    for (int tn = 0; tn < 4; ++tn) {
        #pragma unroll
        for (int to = 0; to < 4; ++to) {
            int col = o0 + wo * 64 + to * 16 + lm;
            float bv = bias[col];
            #pragma unroll
            for (int rr = 0; rr < 4; ++rr) {
                int row = n0 + wn * 64 + tn * 16 + lq * 4 + rr;
                float val = acc[tn][to][rr] + bv;
                if (sig) val = 1.f / (1.f + __expf(-val));
                out[(size_t)row * DDIM + col] = val;
            }
        }
    }
}

// ---------------- recurrence: chunked linear scan ----------------
#define RC_CH 16
#define RC_L  (TDIM / RC_CH)      // 128
#define NCHAIN (BDIM * DDIM)      // 4096

__global__ void rec_pass1(const float* __restrict__ z, const float* __restrict__ hb,
                          float* __restrict__ Aout, float* __restrict__ Bout) {
    int tid = blockIdx.x * blockDim.x + threadIdx.x;
    int c = tid >> 12;
    int chain = tid & 4095;
    int b = chain >> 9, d = chain & 511;
    int base = ((b * TDIM) + c * RC_L) * DDIM + d;
    float ap = 1.f, h = 0.f;
    for (int s = 0; s < RC_L; ++s) {
        float zz = z[base];
        float hh = hb[base];
        float a = 1.f - zz;
        h = fmaf(a, h, zz * hh);
        ap *= a;
        base += DDIM;
    }
    Aout[c * NCHAIN + chain] = ap;
    Bout[c * NCHAIN + chain] = h;
}

__global__ void rec_pass2(const float* __restrict__ A, const float* __restrict__ Bv,
                          float* __restrict__ hstart) {
    int chain = blockIdx.x * blockDim.x + threadIdx.x;
    if (chain >= NCHAIN) return;
    float h = 0.f;
    #pragma unroll
    for (int c = 0; c < RC_CH; ++c) {
        hstart[c * NCHAIN + chain] = h;
        h = fmaf(A[c * NCHAIN + chain], h, Bv[c * NCHAIN + chain]);
    }
}

__global__ void rec_pass3(float* __restrict__ z, const float* __restrict__ hb,
                          const float* __restrict__ hstart) {
    int tid = blockIdx.x * blockDim.x + threadIdx.x;
    int c = tid >> 12;
    int chain = tid & 4095;
    int b = chain >> 9, d = chain & 511;
    int base = ((b * TDIM) + c * RC_L) * DDIM + d;
    float h = hstart[c * NCHAIN + chain];
    for (int s = 0; s < RC_L; ++s) {
        float zz = z[base];
        float hh = hb[base];
        h = fmaf(1.f - zz, h, zz * hh);
        z[base] = h;
        base += DDIM;
    }
}

// ---------------- maxabs norm: one wave per row ----------------
__global__ void norm_kernel(const float* __restrict__ h, float* __restrict__ out) {
    int wave = threadIdx.x >> 6;
    int lane = threadIdx.x & 63;
    int n = blockIdx.x * 4 + wave;
    const float4* row = (const float4*)&h[(size_t)n * DDIM];
    float4 v0 = row[lane];
    float4 v1 = row[lane + 64];
    float m = fmaxf(fmaxf(fabsf(v0.x), fabsf(v0.y)), fmaxf(fabsf(v0.z), fabsf(v0.w)));
    m = fmaxf(m, fmaxf(fmaxf(fabsf(v1.x), fabsf(v1.y)), fmaxf(fabsf(v1.z), fabsf(v1.w))));
    #pragma unroll
    for (int off = 32; off; off >>= 1) m = fmaxf(m, __shfl_xor(m, off, 64));
    float s = 1.0f / (m + EPSF);
    float4* orow = (float4*)&out[(size_t)n * DDIM];
    orow[lane]      = make_float4(v0.x * s, v0.y * s, v0.z * s, v0.w * s);
    orow[lane + 64] = make_float4(v1.x * s, v1.y * s, v1.z * s, v1.w * s);
}

// ---------------- orchestration ----------------
extern "C" void kernel_launch(void* const* d_in, const int* in_sizes, int n_in,
                              void* d_out, int out_size, void* d_ws, size_t ws_size,
                              hipStream_t stream) {
    const float* x   = (const float*)d_in[0];
    const float* pz0 = (const float*)d_in[1];
    const float* vz0 = (const float*)d_in[2];
    const float* ph0 = (const float*)d_in[3];
    const float* vh0 = (const float*)d_in[4];
    const float* pz1 = (const float*)d_in[5];
    const float* vz1 = (const float*)d_in[6];
    const float* ph1 = (const float*)d_in[7];
    const float* vh1 = (const float*)d_in[8];
    const float* po  = (const float*)d_in[9];
    const float* vo  = (const float*)d_in[10];

    float* out_r = (float*)d_out;
    float* h1_r  = out_r + (size_t)NTOK * DDIM;
    float* h2_r  = h1_r + (size_t)NTOK * DDIM;

    char* wp = (char*)d_ws;
    unsigned short* Wtt = (unsigned short*)wp; wp += (size_t)KDIM * DDIM * 2;  // 4 MB
    float2* prm = (float2*)wp; wp += (size_t)KDIM * 8;                        // 32 KB
    float* bias = (float*)wp;  wp += DDIM * 4;
    float* actT = (float*)wp;  wp += (size_t)DDIM * NTOK * 4;                 // 33.5 MB
    float* Ab   = (float*)wp;  wp += RC_CH * NCHAIN * 4;
    float* Bb   = (float*)wp;  wp += RC_CH * NCHAIN * 4;
    float* hs   = (float*)wp;  wp += RC_CH * NCHAIN * 4;

    dim3 gemm_grid(DDIM / 128, NTOK / 128);   // (4, 128)
    dim3 tr_grid(DDIM / 64, NTOK / 64);       // (8, 256)

    auto apl = [&](const float* pts, const float* v, float* o, int sig) {
        prep_params_kernel<<<2, 256, 0, stream>>>(pts, prm);
        prep_wtt_kernel<<<(KDIM / 8) * DDIM / 256, 256, 0, stream>>>(v, Wtt);
        prep_bias_kernel<<<2, 256, 0, stream>>>(v, bias);
        apl_gemm_mfma<<<gemm_grid, 256, 0, stream>>>(actT, Wtt, prm, bias, o, sig);
    };
    auto recur = [&](float* zb, float* hb) {
        rec_pass1<<<(RC_CH * NCHAIN) / 256, 256, 0, stream>>>(zb, hb, Ab, Bb);
        rec_pass2<<<NCHAIN / 256, 256, 0, stream>>>(Ab, Bb, hs);
        rec_pass3<<<(RC_CH * NCHAIN) / 256, 256, 0, stream>>>(zb, hb, hs);
    };

    // layer 1
    transpose_kernel<<<tr_grid, 256, 0, stream>>>(x, actT);
    apl(pz0, vz0, out_r, 1);          // z (sigmoid) -> out_r
    apl(ph0, vh0, h1_r, 0);           // h_bar -> h1_r slot
    recur(out_r, h1_r);               // h -> out_r
    norm_kernel<<<NTOK / 4, 256, 0, stream>>>(out_r, h1_r);
    // layer 2
    transpose_kernel<<<tr_grid, 256, 0, stream>>>(h1_r, actT);
    apl(pz1, vz1, out_r, 1);
    apl(ph1, vh1, h2_r, 0);
    recur(out_r, h2_r);
    norm_kernel<<<NTOK / 4, 256, 0, stream>>>(out_r, h2_r);
    // output APL
    transpose_kernel<<<tr_grid, 256, 0, stream>>>(h2_r, actT);
    apl(po, vo, out_r, 0);
}

// Round 4
// 644.742 us; speedup vs baseline: 6.4307x; 1.3478x over previous
//
#include <hip/hip_runtime.h>
#include <hip/hip_bf16.h>
#include <math.h>

#define BDIM   8
#define TDIM   2048
#define DDIM   512
#define PDIM   8
#define NTOK   (BDIM * TDIM)        // 16384
#define KDIM   (DDIM * PDIM)        // 4096
#define EPSF   1e-6f

typedef __attribute__((ext_vector_type(4))) float floatx4;
typedef __attribute__((ext_vector_type(8))) _Float16 half8;
typedef __attribute__((ext_vector_type(2))) _Float16 half2v;

// ================= prep (all 5 APL layers, hoisted) =================
// prmh[layer][i*16 + 0..7]  = fp16 inv for p=0..7   (p=0: 0)
// prmh[layer][i*16 + 8..15] = fp16 ofs for p=0..7   (p=0: 1)
__global__ void prep_prmh_kernel(const float* p0, const float* p1,
                                 const float* p2, const float* p3,
                                 const float* p4,
                                 unsigned short* __restrict__ prmh) {
    int layer = blockIdx.x;
    int i = threadIdx.x;  // 0..511
    const float* pts = layer == 0 ? p0 : layer == 1 ? p1 : layer == 2 ? p2
                     : layer == 3 ? p3 : p4;
    unsigned short* dst = prmh + (size_t)layer * DDIM * 16 + (size_t)i * 16;
    _Float16 invh[8], ofsh[8];
    invh[0] = (_Float16)0.f; ofsh[0] = (_Float16)1.f;
    #pragma unroll
    for (int p = 1; p < 8; ++p) {
        float a = pts[i * 8 + p - 1];
        float b = pts[i * 8 + p];
        float inv = 1.0f / (b - a);
        invh[p] = (_Float16)inv;
        ofsh[p] = (_Float16)(-a * inv);
    }
    *(uint4*)(dst)     = *(const uint4*)invh;
    *(uint4*)(dst + 8) = *(const uint4*)ofsh;
}

// W -> fp16, first-differenced, k-octet-interleaved; p=0 col zeroed (bias)
__global__ void prep_wtt_kernel(const float* v0, const float* v1,
                                const float* v2, const float* v3,
                                const float* v4,
                                unsigned short* __restrict__ Wtt_all) {
    int layer = blockIdx.y;
    const float* v = layer == 0 ? v0 : layer == 1 ? v1 : layer == 2 ? v2
                   : layer == 3 ? v3 : v4;
    unsigned short* Wtt = Wtt_all + (size_t)layer * KDIM * DDIM;
    int idx = blockIdx.x * blockDim.x + threadIdx.x;   // oct*512 + o
    int oct = idx >> 9, o = idx & 511;
    unsigned short f8[8];
    float prev = v[(size_t)(oct * 8) * DDIM + o];
    f8[0] = 0;
    #pragma unroll
    for (int p = 1; p < 8; ++p) {
        float cur = v[(size_t)(oct * 8 + p) * DDIM + o];
        float d = cur - prev;
        prev = cur;
        _Float16 hv = (_Float16)d;
        f8[p] = *reinterpret_cast<unsigned short*>(&hv);
    }
    *(uint4*)&Wtt[(size_t)idx * 8] = *(const uint4*)f8;
}

// bias[layer][o] = sum_i v[i][0][o]  (exact fp32 for the constant column)
__global__ void prep_bias_kernel(const float* v0, const float* v1,
                                 const float* v2, const float* v3,
                                 const float* v4,
                                 float* __restrict__ bias_all) {
    int layer = blockIdx.x;
    const float* v = layer == 0 ? v0 : layer == 1 ? v1 : layer == 2 ? v2
                   : layer == 3 ? v3 : v4;
    int o = threadIdx.x;
    float s = 0.f;
    for (int i = 0; i < DDIM; ++i) s += v[(size_t)i * PDIM * DDIM + o];
    bias_all[layer * DDIM + o] = s;
}

// ================= fused ramp-feature MFMA GEMM =================
// Reads act in natural (N, D) layout. blockIdx.z selects param set
// (z-gate vs h_bar), so both GEMMs of a layer run in one dispatch.
__launch_bounds__(256, 4)
__global__ void apl_gemm_mfma(const float* __restrict__ act,       // (N, D)
                              const unsigned short* __restrict__ WttA,
                              const unsigned short* __restrict__ WttB,
                              const unsigned short* __restrict__ prmA,
                              const unsigned short* __restrict__ prmB,
                              const float* __restrict__ biasA,
                              const float* __restrict__ biasB,
                              float* __restrict__ outA,
                              float* __restrict__ outB,
                              int sigA, int sigB) {
    __shared__ unsigned short As[128 * 40];      // [n][k], stride 40
    __shared__ unsigned short Bs[4 * 128 * 8];   // [k-octet][o][p]

    const int zi = blockIdx.z;
    const unsigned short* Wtt = zi ? WttB : WttA;
    const unsigned short* prm = zi ? prmB : prmA;
    const float* bias = zi ? biasB : biasA;
    float* out = zi ? outB : outA;
    const int sig = zi ? sigB : sigA;

    const int t = threadIdx.x;
    const int w = t >> 6, l = t & 63;
    const int o0 = blockIdx.x * 128, n0 = blockIdx.y * 128;
    const int wn = w & 1, wo = w >> 1;
    const int lm = l & 15, lq = l >> 4;
    // permute staging roles by block parity to spread VALU across SIMDs
    const int pw = (w + ((blockIdx.x + blockIdx.y) & 1) * 2) & 3;

    const half2v h2zero = {(_Float16)0.f, (_Float16)0.f};
    const half2v h2one  = {(_Float16)1.f, (_Float16)1.f};

    floatx4 acc[4][4];
    #pragma unroll
    for (int a = 0; a < 4; ++a)
        #pragma unroll
        for (int b = 0; b < 4; ++b) acc[a][b] = (floatx4){0.f, 0.f, 0.f, 0.f};

    for (int iter = 0; iter < KDIM / 32; ++iter) {
        const int i0 = iter * 4;
        if (pw < 2) {
            // ---- A role: n = pw*64 + l; 4 dims -> 32 fp16 ramp features
            const int n = pw * 64 + l;
            float4 xq = *(const float4*)&act[(size_t)(n0 + n) * DDIM + i0];
            float xs[4] = {xq.x, xq.y, xq.z, xq.w};
            #pragma unroll
            for (int j = 0; j < 4; ++j) {
                const unsigned short* pb = prm + (size_t)(i0 + j) * 16;
                uint4 iv = *(const uint4*)pb;        // 4x half2 inv
                uint4 ov = *(const uint4*)(pb + 8);  // 4x half2 ofs
                _Float16 xh = (_Float16)xs[j];
                half2v x2 = {xh, xh};
                unsigned int invw[4] = {iv.x, iv.y, iv.z, iv.w};
                unsigned int ofsw[4] = {ov.x, ov.y, ov.z, ov.w};
                unsigned int fw[4];
                #pragma unroll
                for (int pp = 0; pp < 4; ++pp) {
                    half2v in2 = __builtin_bit_cast(half2v, invw[pp]);
                    half2v of2 = __builtin_bit_cast(half2v, ofsw[pp]);
                    half2v tt = x2 * in2 + of2;                 // v_pk_fma_f16
                    tt = __builtin_elementwise_max(tt, h2zero);
                    tt = __builtin_elementwise_min(tt, h2one);
                    fw[pp] = __builtin_bit_cast(unsigned int, tt);
                }
                uint4 pk = {fw[0], fw[1], fw[2], fw[3]};
                *(uint4*)&As[n * 40 + j * 8] = pk;
            }
        } else {
            // ---- B role: u = (pw-2)*64 + l; copy Wtt tile (already fp16)
            const int u = (pw - 2) * 64 + l;
            #pragma unroll
            for (int j = 0; j < 4; ++j) {
                uint4 bv = *(const uint4*)&Wtt[((size_t)(i0 + j) * DDIM + o0 + u) * 8];
                *(uint4*)&Bs[j * 1024 + u * 8] = bv;
            }
        }
        __syncthreads();

        half8 af[4], bfr[4];
        #pragma unroll
        for (int tn = 0; tn < 4; ++tn)
            af[tn] = *(const half8*)&As[(wn * 64 + tn * 16 + lm) * 40 + lq * 8];
        #pragma unroll
        for (int to = 0; to < 4; ++to)
            bfr[to] = *(const half8*)&Bs[lq * 1024 + (wo * 64 + to * 16 + lm) * 8];
        #pragma unroll
        for (int tn = 0; tn < 4; ++tn)
            #pragma unroll
            for (int to = 0; to < 4; ++to)
                acc[tn][to] = __builtin_amdgcn_mfma_f32_16x16x32_f16(
                    af[tn], bfr[to], acc[tn][to], 0, 0, 0);
        __syncthreads();
    }

    // epilogue: C/D layout col=lane&15, row=(lane>>4)*4+reg; fp32 bias
    #pragma unroll
    for (int tn = 0; tn < 4; ++tn) {
        #pragma unroll
        for (int to = 0; to < 4; ++to) {
            int col = o0 + wo * 64 + to * 16 + lm;
            float bv = bias[col];
            #pragma unroll
            for (int rr = 0; rr < 4; ++rr) {
                int row = n0 + wn * 64 + tn * 16 + lq * 4 + rr;
                float val = acc[tn][to][rr] + bv;
                if (sig) val = 1.f / (1.f + __expf(-val));
                out[(size_t)row * DDIM + col] = val;
            }
        }
    }
}

// ================= recurrence: chunked linear scan =================
#define RC_CH 16
#define RC_L  (TDIM / RC_CH)      // 128
#define NCHAIN (BDIM * DDIM)      // 4096

__global__ void rec_pass1(const float* __restrict__ z, const float* __restrict__ hb,
                          float* __restrict__ Aout, float* __restrict__ Bout) {
    int tid = blockIdx.x * blockDim.x + threadIdx.x;
    int c = tid >> 12;
    int chain = tid & 4095;
    int b = chain >> 9, d = chain & 511;
    int base = ((b * TDIM) + c * RC_L) * DDIM + d;
    float ap = 1.f, h = 0.f;
    for (int s = 0; s < RC_L; ++s) {
        float zz = z[base];
        float hh = hb[base];
        float a = 1.f - zz;
        h = fmaf(a, h, zz * hh);
        ap *= a;
        base += DDIM;
    }
    Aout[c * NCHAIN + chain] = ap;
    Bout[c * NCHAIN + chain] = h;
}

__global__ void rec_pass2(const float* __restrict__ A, const float* __restrict__ Bv,
                          float* __restrict__ hstart) {
    int chain = blockIdx.x * blockDim.x + threadIdx.x;
    if (chain >= NCHAIN) return;
    float h = 0.f;
    #pragma unroll
    for (int c = 0; c < RC_CH; ++c) {
        hstart[c * NCHAIN + chain] = h;
        h = fmaf(A[c * NCHAIN + chain], h, Bv[c * NCHAIN + chain]);
    }
}

__global__ void rec_pass3(float* __restrict__ z, const float* __restrict__ hb,
                          const float* __restrict__ hstart) {
    int tid = blockIdx.x * blockDim.x + threadIdx.x;
    int c = tid >> 12;
    int chain = tid & 4095;
    int b = chain >> 9, d = chain & 511;
    int base = ((b * TDIM) + c * RC_L) * DDIM + d;
    float h = hstart[c * NCHAIN + chain];
    for (int s = 0; s < RC_L; ++s) {
        float zz = z[base];
        float hh = hb[base];
        h = fmaf(1.f - zz, h, zz * hh);
        z[base] = h;
        base += DDIM;
    }
}

// ================= maxabs norm: one wave per row =================
__global__ void norm_kernel(const float* __restrict__ h, float* __restrict__ out) {
    int wave = threadIdx.x >> 6;
    int lane = threadIdx.x & 63;
    int n = blockIdx.x * 4 + wave;
    const float4* row = (const float4*)&h[(size_t)n * DDIM];
    float4 v0 = row[lane];
    float4 v1 = row[lane + 64];
    float m = fmaxf(fmaxf(fabsf(v0.x), fabsf(v0.y)), fmaxf(fabsf(v0.z), fabsf(v0.w)));
    m = fmaxf(m, fmaxf(fmaxf(fabsf(v1.x), fabsf(v1.y)), fmaxf(fabsf(v1.z), fabsf(v1.w))));
    #pragma unroll
    for (int off = 32; off; off >>= 1) m = fmaxf(m, __shfl_xor(m, off, 64));
    float s = 1.0f / (m + EPSF);
    float4* orow = (float4*)&out[(size_t)n * DDIM];
    orow[lane]      = make_float4(v0.x * s, v0.y * s, v0.z * s, v0.w * s);
    orow[lane + 64] = make_float4(v1.x * s, v1.y * s, v1.z * s, v1.w * s);
}

// ================= orchestration =================
extern "C" void kernel_launch(void* const* d_in, const int* in_sizes, int n_in,
                              void* d_out, int out_size, void* d_ws, size_t ws_size,
                              hipStream_t stream) {
    const float* x   = (const float*)d_in[0];
    const float* pz0 = (const float*)d_in[1];
    const float* vz0 = (const float*)d_in[2];
    const float* ph0 = (const float*)d_in[3];
    const float* vh0 = (const float*)d_in[4];
    const float* pz1 = (const float*)d_in[5];
    const float* vz1 = (const float*)d_in[6];
    const float* ph1 = (const float*)d_in[7];
    const float* vh1 = (const float*)d_in[8];
    const float* po  = (const float*)d_in[9];
    const float* vo  = (const float*)d_in[10];

    float* out_r = (float*)d_out;
    float* h1_r  = out_r + (size_t)NTOK * DDIM;
    float* h2_r  = h1_r + (size_t)NTOK * DDIM;

    char* wp = (char*)d_ws;
    unsigned short* Wtt = (unsigned short*)wp; wp += (size_t)5 * KDIM * DDIM * 2;  // 20 MB
    unsigned short* prm = (unsigned short*)wp; wp += (size_t)5 * DDIM * 16 * 2;    // 80 KB
    float* bias = (float*)wp;  wp += 5 * DDIM * 4;
    float* Ab   = (float*)wp;  wp += RC_CH * NCHAIN * 4;
    float* Bb   = (float*)wp;  wp += RC_CH * NCHAIN * 4;
    float* hs   = (float*)wp;  wp += RC_CH * NCHAIN * 4;

    const size_t WS = (size_t)KDIM * DDIM;   // Wtt slot stride
    const size_t PS = (size_t)DDIM * 16;     // prm slot stride

    // -------- all param prep up front (layers: 0=z0 1=h0 2=z1 3=h1 4=out)
    prep_prmh_kernel<<<5, 512, 0, stream>>>(pz0, ph0, pz1, ph1, po, prm);
    prep_wtt_kernel<<<dim3((KDIM / 8) * DDIM / 256, 5), 256, 0, stream>>>(
        vz0, vh0, vz1, vh1, vo, Wtt);
    prep_bias_kernel<<<5, 512, 0, stream>>>(vz0, vh0, vz1, vh1, vo, bias);

    dim3 gemm2(DDIM / 128, NTOK / 128, 2);   // merged z+h: 1024 blocks
    dim3 gemm1(DDIM / 128, NTOK / 128, 1);

    auto recur = [&](float* zb, float* hb) {
        rec_pass1<<<(RC_CH * NCHAIN) / 256, 256, 0, stream>>>(zb, hb, Ab, Bb);
        rec_pass2<<<NCHAIN / 256, 256, 0, stream>>>(Ab, Bb, hs);
        rec_pass3<<<(RC_CH * NCHAIN) / 256, 256, 0, stream>>>(zb, hb, hs);
    };

    // layer 1: z -> out_r (sigmoid), h_bar -> h1_r
    apl_gemm_mfma<<<gemm2, 256, 0, stream>>>(
        x, Wtt, Wtt + WS, prm, prm + PS, bias, bias + DDIM,
        out_r, h1_r, 1, 0);
    recur(out_r, h1_r);
    norm_kernel<<<NTOK / 4, 256, 0, stream>>>(out_r, h1_r);

    // layer 2
    apl_gemm_mfma<<<gemm2, 256, 0, stream>>>(
        h1_r, Wtt + 2 * WS, Wtt + 3 * WS, prm + 2 * PS, prm + 3 * PS,
        bias + 2 * DDIM, bias + 3 * DDIM, out_r, h2_r, 1, 0);
    recur(out_r, h2_r);
    norm_kernel<<<NTOK / 4, 256, 0, stream>>>(out_r, h2_r);

    // output APL
    apl_gemm_mfma<<<gemm1, 256, 0, stream>>>(
        h2_r, Wtt + 4 * WS, Wtt + 4 * WS, prm + 4 * PS, prm + 4 * PS,
        bias + 4 * DDIM, bias + 4 * DDIM, out_r, out_r, 0, 0);
}